// Round 6
// baseline (108.100 us; speedup 1.0000x reference)
//
#include <hip/hip_runtime.h>

#define H  4096
#define W  8192
#define KH 3
#define KW 3
#define HO (H - KH + 1)   // 4094
#define WO (W - KW + 1)   // 8190
#define CPT 4             // output cols per thread
#define RPS 4             // output rows per strip
#define SPB 4             // strips per block band
#define BAND (RPS * SPB)  // 16 output rows per block
#define BLK 256

__global__ __launch_bounds__(BLK, 8) void ConvLayer_4140348473931_kernel(
    const float* __restrict__ X, const float* __restrict__ Wt,
    const float* __restrict__ Bias, float* __restrict__ Out)
{
    const int tid   = threadIdx.x;
    const int c0    = blockIdx.x * (BLK * CPT) + tid * CPT;  // multiple of 4
    const int rbase = blockIdx.y * BAND;
    // last thread (c0=8188) would read cols 8192/8193; clamp the float2 to W-2.
    // Wrong lanes feed only outputs >= WO which are masked.
    const int cext  = min(c0 + 4, W - 2);

    float w[9];
#pragma unroll
    for (int i = 0; i < 9; ++i) w[i] = Wt[i];
    const float bias = Bias[0];

    float x[6][6];      // rolling window: 6 input rows x 6 cols
    float preA[4][6];   // prefetch ping
    float preB[4][6];   // prefetch pong

#define LOADROW(rr, dst)                                                     \
    do {                                                                     \
        int _r = (rr); if (_r > H - 1) _r = H - 1;                           \
        const float* _row = X + (size_t)_r * W;                              \
        float4 _v  = *reinterpret_cast<const float4*>(_row + c0);            \
        float2 _v2 = *reinterpret_cast<const float2*>(_row + cext);          \
        (dst)[0] = _v.x;  (dst)[1] = _v.y;  (dst)[2] = _v.z;                 \
        (dst)[3] = _v.w;  (dst)[4] = _v2.x; (dst)[5] = _v2.y;                \
    } while (0)

    // prefetch for strip t loads its 4 NEW rows: rbase + t*RPS + 2 .. +5
#define PREFETCH(t, buf)                                                     \
    do {                                                                     \
        if ((t) < SPB) {                                                     \
            _Pragma("unroll")                                                \
            for (int _ir = 0; _ir < RPS; ++_ir)                              \
                LOADROW(rbase + (t) * RPS + 2 + _ir, (buf)[_ir]);            \
        }                                                                    \
    } while (0)

#define COMPUTE_STORE(s)                                                     \
    do {                                                                     \
        float acc[RPS][CPT];                                                 \
        _Pragma("unroll")                                                    \
        for (int _i = 0; _i < RPS; ++_i) {                                   \
            _Pragma("unroll")                                                \
            for (int _j = 0; _j < CPT; ++_j) {                               \
                float _s = bias;                                             \
                _Pragma("unroll")                                            \
                for (int _kh = 0; _kh < KH; ++_kh)                           \
                    _Pragma("unroll")                                        \
                    for (int _kw = 0; _kw < KW; ++_kw)                       \
                        _s = fmaf(w[_kh * 3 + _kw], x[_i + _kh][_j + _kw], _s); \
                acc[_i][_j] = _s;                                            \
            }                                                                \
        }                                                                    \
        const int _r0 = rbase + (s) * RPS;                                   \
        const bool _full = (c0 + CPT <= WO);                                 \
        _Pragma("unroll")                                                    \
        for (int _i = 0; _i < RPS; ++_i) {                                   \
            int _r = _r0 + _i;                                               \
            if (_r < HO) {                                                   \
                float* _orow = Out + (size_t)_r * WO + c0;                   \
                *reinterpret_cast<float2*>(_orow) = make_float2(acc[_i][0], acc[_i][1]); \
                if (_full)                                                   \
                    *reinterpret_cast<float2*>(_orow + 2) = make_float2(acc[_i][2], acc[_i][3]); \
            }                                                                \
        }                                                                    \
    } while (0)

#define SHIFT_FROM(buf)                                                      \
    do {                                                                     \
        _Pragma("unroll")                                                    \
        for (int _j = 0; _j < 6; ++_j) { x[0][_j] = x[4][_j]; x[1][_j] = x[5][_j]; } \
        _Pragma("unroll")                                                    \
        for (int _ir = 0; _ir < RPS; ++_ir)                                  \
            _Pragma("unroll")                                                \
            for (int _j = 0; _j < 6; ++_j) x[2 + _ir][_j] = (buf)[_ir][_j];  \
    } while (0)

    // pipeline fill: strip 0 window + strip 1's new rows
#pragma unroll
    for (int ir = 0; ir < 6; ++ir) LOADROW(rbase + ir, x[ir]);
    PREFETCH(1, preA);

    // main loop, strips in pairs so preA/preB roles are static (no runtime idx)
#pragma unroll
    for (int p = 0; p < SPB / 2; ++p) {
        const int s0 = 2 * p;
        PREFETCH(s0 + 2, preB);       // 2-deep: issue strip s0+2 loads now
        COMPUTE_STORE(s0);
        SHIFT_FROM(preA);             // waits on preA (issued 2 strips ago)

        PREFETCH(s0 + 3, preA);       // issue strip s0+3 loads
        COMPUTE_STORE(s0 + 1);
        if (s0 + 2 < SPB) SHIFT_FROM(preB);
    }

#undef LOADROW
#undef PREFETCH
#undef COMPUTE_STORE
#undef SHIFT_FROM
}

extern "C" void kernel_launch(void* const* d_in, const int* in_sizes, int n_in,
                              void* d_out, int out_size, void* d_ws, size_t ws_size,
                              hipStream_t stream) {
    const float* X    = (const float*)d_in[0];
    const float* Wt   = (const float*)d_in[1];
    const float* Bias = (const float*)d_in[2];
    float* Out        = (float*)d_out;

    dim3 block(BLK);
    dim3 grid((WO + BLK * CPT - 1) / (BLK * CPT),   // 8  -> XCD = bx (column stripe per XCD)
              (HO + BAND - 1) / BAND);              // 256 -> 2048 blocks = 8 blocks/CU = 32 waves/CU
    ConvLayer_4140348473931_kernel<<<grid, block, 0, stream>>>(X, Wt, Bias, Out);
}

// Round 7
// 56.850 us; speedup vs baseline: 1.9015x; 1.9015x over previous
//
#include <hip/hip_runtime.h>

#define H  4096
#define W  8192
#define HO (H - 2)        // 4094
#define WO (W - 2)        // 8190
#define TW 256            // output cols per block
#define TH 16             // output rows per block
#define IH (TH + 2)       // 18 staged input rows
#define LDW 264           // LDS row stride in floats (pad 258 -> 264)
#define BLK 256

__global__ __launch_bounds__(BLK, 4) void ConvLayer_4140348473931_kernel(
    const float* __restrict__ X, const float* __restrict__ Wt,
    const float* __restrict__ Bias, float* __restrict__ Out)
{
    __shared__ float lds[IH][LDW];   // 18*264*4 = 19008 B -> 8 blocks/CU by LDS

    const int tid  = threadIdx.x;
    const int lane = tid & 63;
    const int wav  = tid >> 6;

    const int C0 = blockIdx.x * TW;
    const int R0 = blockIdx.y * TH;

    // ---- load phase: 18 rows x 258 cols, coalesced float4 sweeps ----
    // wave w loads rows w, w+4, w+8, ...; lane i loads float4 at col 4i.
    // tail cols 256,257 by lane 0 (clamped at the right edge; the wrong
    // values feed only outputs >= WO which are masked on store).
    const int ctail = min(C0 + TW, W - 2);
#pragma unroll
    for (int k = 0; k < 5; ++k) {
        const int r = wav + 4 * k;
        if (r < IH) {
            int gr = R0 + r; if (gr > H - 1) gr = H - 1;   // bottom-edge clamp (masked outputs)
            const float* row = X + (size_t)gr * W;
            float4 v = *reinterpret_cast<const float4*>(row + C0 + 4 * lane);
            *reinterpret_cast<float4*>(&lds[r][4 * lane]) = v;
            if (lane == 0) {
                float2 t = *reinterpret_cast<const float2*>(row + ctail);
                lds[r][TW]     = t.x;
                lds[r][TW + 1] = t.y;
            }
        }
    }

    // uniform weights + bias (scalar)
    float w[9];
#pragma unroll
    for (int i = 0; i < 9; ++i) w[i] = Wt[i];
    const float bias = Bias[0];

    __syncthreads();

    // ---- compute phase: each thread owns a 4x4 output block ----
    const int colseg = tid & 63;       // 64 segments of 4 cols
    const int rowgrp = tid >> 6;       // 4 groups of 4 rows
    const int lc = colseg * 4;
    const int lr = rowgrp * 4;

    float acc[4][4];
#pragma unroll
    for (int i = 0; i < 4; ++i)
#pragma unroll
        for (int j = 0; j < 4; ++j) acc[i][j] = bias;

    // stream 6 input rows; row ir contributes to output rows i with kh=ir-i in [0,3)
#pragma unroll
    for (int ir = 0; ir < 6; ++ir) {
        // two b128 reads: conflict-free contiguous sweeps (lane-stride 16B)
        float4 a = *reinterpret_cast<const float4*>(&lds[lr + ir][lc]);
        float4 b = *reinterpret_cast<const float4*>(&lds[lr + ir][lc + 4]);
        const float xw[6] = {a.x, a.y, a.z, a.w, b.x, b.y};
#pragma unroll
        for (int i = 0; i < 4; ++i) {
            const int kh = ir - i;
            if (kh >= 0 && kh < 3) {
#pragma unroll
                for (int j = 0; j < 4; ++j) {
                    float s = acc[i][j];
                    s = fmaf(w[kh * 3 + 0], xw[j + 0], s);
                    s = fmaf(w[kh * 3 + 1], xw[j + 1], s);
                    s = fmaf(w[kh * 3 + 2], xw[j + 2], s);
                    acc[i][j] = s;
                }
            }
        }
    }

    // ---- store: float2 pairs (r*8190 + oc always even -> 8B aligned) ----
    const int oc = C0 + lc;
    const bool full = (oc + 4 <= WO);
#pragma unroll
    for (int i = 0; i < 4; ++i) {
        const int r = R0 + lr + i;
        if (r < HO) {
            float* orow = Out + (size_t)r * WO + oc;
            if (full) {
                *reinterpret_cast<float2*>(orow)     = make_float2(acc[i][0], acc[i][1]);
                *reinterpret_cast<float2*>(orow + 2) = make_float2(acc[i][2], acc[i][3]);
            } else {
#pragma unroll
                for (int j = 0; j < 4; ++j)
                    if (oc + j < WO) orow[j] = acc[i][j];
            }
        }
    }
}

extern "C" void kernel_launch(void* const* d_in, const int* in_sizes, int n_in,
                              void* d_out, int out_size, void* d_ws, size_t ws_size,
                              hipStream_t stream) {
    const float* X    = (const float*)d_in[0];
    const float* Wt   = (const float*)d_in[1];
    const float* Bias = (const float*)d_in[2];
    float* Out        = (float*)d_out;

    dim3 block(BLK);
    dim3 grid((WO + TW - 1) / TW,    // 32  (bx fastest -> vertical-halo neighbors land on same XCD)
              (HO + TH - 1) / TH);   // 256 -> 8192 blocks, ~8/CU resident (LDS-capped)
    ConvLayer_4140348473931_kernel<<<grid, block, 0, stream>>>(X, Wt, Bias, Out);
}